// Round 5
// baseline (141.822 us; speedup 1.0000x reference)
//
#include <hip/hip_runtime.h>
#include <hip/hip_bf16.h>

// Sinusoidal positional encoding, broadcast to (n, 1, length).
// length = 8192, n = 4096 (fixed). Output float32 (134.2 MB pure stores).
//
// R3 post-mortem: dur_us (~139) includes ~103 us of harness 0xAA poison
// fills (512 MiB d_ws @ 82 us + 128 MiB d_out @ ~20 us — top-5 profile rows
// are all fills; my kernels never appear, so each is <81 us). Controllable
// slice ~36 us vs ~25 us floor (134 MB @ 6.5 TB/s + launch). Compute is
// irrelevant (R2 fused == R3 split).
//
// R4: __builtin_nontemporal_store rejects HIP_vector_type float4 -> use a
// clang native ext_vector_type(4) float. Single fused kernel + nt stores.

#define LENGTH 8192
#define NROWS  4096

#define THREADS        256
#define COLS_PER_THR   4
#define COLS_PER_BLK   (THREADS * COLS_PER_THR)   // 1024
#define COL_BLKS       (LENGTH / COLS_PER_BLK)    // 8
#define ROW_BLKS       256
#define ROWS_PER_BLK   (NROWS / ROW_BLKS)         // 16

typedef float vfloat4 __attribute__((ext_vector_type(4)));

__global__ __launch_bounds__(THREADS)
void Sinusoidal_84198538871038_kernel(const float* __restrict__ pos_p,
                                      float* __restrict__ out) {
    const float position = pos_p[0];

    const int colblk = blockIdx.x & (COL_BLKS - 1);
    const int rowblk = blockIdx.x >> 3;            // / COL_BLKS
    const int col0   = colblk * COLS_PER_BLK + threadIdx.x * COLS_PER_THR;

    // 1000^(-i/length) = exp(i * (-ln(1000)/length))
    const float kNegLn1000OverL = -6.90775527898213705f / (float)LENGTH;

    vfloat4 v;
    const float a0 = position * expf((float)(col0)     * kNegLn1000OverL);
    const float a1 = position * expf((float)(col0 + 2) * kNegLn1000OverL);
    v.x = sinf(a0);
    v.y = cosf(a0);
    v.z = sinf(a1);
    v.w = cosf(a1);

    const size_t base = (size_t)rowblk * ROWS_PER_BLK * LENGTH + (size_t)col0;
#pragma unroll
    for (int r = 0; r < ROWS_PER_BLK; ++r) {
        __builtin_nontemporal_store(v, reinterpret_cast<vfloat4*>(out + base + (size_t)r * LENGTH));
    }
}

extern "C" void kernel_launch(void* const* d_in, const int* in_sizes, int n_in,
                              void* d_out, int out_size, void* d_ws, size_t ws_size,
                              hipStream_t stream) {
    // d_in[0] = length (int) -- fixed 8192
    // d_in[1] = n      (int) -- fixed 4096
    // d_in[2] = position (float, 1 elem)
    const float* pos = (const float*)d_in[2];
    float* out = (float*)d_out;

    Sinusoidal_84198538871038_kernel<<<dim3(COL_BLKS * ROW_BLKS), dim3(THREADS), 0, stream>>>(pos, out);
}

// Round 6
// 137.940 us; speedup vs baseline: 1.0281x; 1.0281x over previous
//
#include <hip/hip_runtime.h>
#include <hip/hip_bf16.h>

// Sinusoidal positional encoding, broadcast to (n, 1, length).
// length = 8192, n = 4096 (fixed). Output float32 (134.2 MB pure stores).
//
// FINAL (R6 = revert to R2 structure, the measured best):
//   Session model, consistent across R2/R3/R5:
//   - dur_us (~139) = ~110 us harness 0xAA poison fills inside the timed
//     region (512 MiB d_ws @ ~88 us + 128 MiB d_out @ ~22 us; top-5 profile
//     rows are always these fills, my kernel never appears -> <86 us) plus
//     ~30 us controllable slice.
//   - Controllable floor: 134.2 MB mandatory stores @ ~6.4 TB/s ~= 21 us
//     + ~4 us launch. We're within ~5 us of it.
//   - Variants measured: fused+libm 138.5 | split 139.5 | fused+nt 141.8.
//     nt stores regressed ~2% (bypassing L2 buffering on a pure store
//     stream); plain coalesced float4 stores are best.
//   - Compute (accurate libm expf/sinf/cosf) is irrelevant: ~175 VALU
//     instrs amortized over 16 stores/thread at 8 waves/SIMD occupancy.

#define LENGTH 8192
#define NROWS  4096

#define THREADS        256
#define COLS_PER_THR   4
#define COLS_PER_BLK   (THREADS * COLS_PER_THR)   // 1024
#define COL_BLKS       (LENGTH / COLS_PER_BLK)    // 8
#define ROW_BLKS       256
#define ROWS_PER_BLK   (NROWS / ROW_BLKS)         // 16

__global__ __launch_bounds__(THREADS)
void Sinusoidal_84198538871038_kernel(const float* __restrict__ pos_p,
                                      float* __restrict__ out) {
    const float position = pos_p[0];

    const int colblk = blockIdx.x & (COL_BLKS - 1);
    const int rowblk = blockIdx.x >> 3;            // / COL_BLKS
    const int col0   = colblk * COLS_PER_BLK + threadIdx.x * COLS_PER_THR;

    // 1000^(-i/length) = exp(i * (-ln(1000)/length))
    const float kNegLn1000OverL = -6.90775527898213705f / (float)LENGTH;

    float4 v;
    const float a0 = position * expf((float)(col0)     * kNegLn1000OverL);
    const float a1 = position * expf((float)(col0 + 2) * kNegLn1000OverL);
    v.x = sinf(a0);
    v.y = cosf(a0);
    v.z = sinf(a1);
    v.w = cosf(a1);

    const size_t base = (size_t)rowblk * ROWS_PER_BLK * LENGTH + (size_t)col0;
#pragma unroll
    for (int r = 0; r < ROWS_PER_BLK; ++r) {
        *reinterpret_cast<float4*>(out + base + (size_t)r * LENGTH) = v;
    }
}

extern "C" void kernel_launch(void* const* d_in, const int* in_sizes, int n_in,
                              void* d_out, int out_size, void* d_ws, size_t ws_size,
                              hipStream_t stream) {
    // d_in[0] = length (int) -- fixed 8192
    // d_in[1] = n      (int) -- fixed 4096
    // d_in[2] = position (float, 1 elem)
    const float* pos = (const float*)d_in[2];
    float* out = (float*)d_out;

    Sinusoidal_84198538871038_kernel<<<dim3(COL_BLKS * ROW_BLKS), dim3(THREADS), 0, stream>>>(pos, out);
}